// Round 8
// baseline (214.084 us; speedup 1.0000x reference)
//
#include <hip/hip_runtime.h>

typedef __bf16 bf16_t;
typedef __bf16 bf16x4 __attribute__((ext_vector_type(4)));
typedef __bf16 bf16x8 __attribute__((ext_vector_type(8)));
typedef float  f32x4  __attribute__((ext_vector_type(4)));
typedef float  f32x16 __attribute__((ext_vector_type(16)));
typedef unsigned int u32;

#define MFMA16(a, b, c) __builtin_amdgcn_mfma_f32_16x16x32_bf16((a), (b), (c), 0, 0, 0)
#define MFMA32(a, b, c) __builtin_amdgcn_mfma_f32_32x32x16_bf16((a), (b), (c), 0, 0, 0)

__device__ __forceinline__ void gld_lds16(const bf16_t* g, bf16_t* l) {
  __builtin_amdgcn_global_load_lds((__attribute__((address_space(1))) void*)g,
                                   (__attribute__((address_space(3))) void*)l, 16, 0, 0);
}
__device__ __forceinline__ u32 cvt_pk_bf16(float lo, float hi) {
  u32 r;
  asm("v_cvt_pk_bf16_f32 %0, %1, %2" : "=v"(r) : "v"(lo), "v"(hi));
  return r;
}

// ---------------- prep: x cast (big) ----------------
__global__ void cast_f32_bf16(const float* __restrict__ s, bf16_t* __restrict__ d, int n) {
  int i = (blockIdx.x * blockDim.x + threadIdx.x) * 4;
  if (i >= n) return;
  float4 v = *(const float4*)(s + i);
  bf16x4 o;
  o[0] = (bf16_t)v.x; o[1] = (bf16_t)v.y; o[2] = (bf16_t)v.z; o[3] = (bf16_t)v.w;
  *(bf16x4*)(d + i) = o;
}

// ---------------- prep: all weight casts + bias concat in one launch ----------------
__global__ void prep_w(const float* __restrict__ Wq, const float* __restrict__ Wk,
                       const float* __restrict__ Wv, const float* __restrict__ Wo,
                       const float* __restrict__ bq, const float* __restrict__ bk,
                       const float* __restrict__ bv,
                       bf16_t* __restrict__ wqkv, bf16_t* __restrict__ wob,
                       float* __restrict__ qkvb) {
  const int NW = 768 * 768;
  const int t = blockIdx.x * 256 + threadIdx.x;
  const int i = t * 4;
  if (i < 3 * NW) {
    const float* s; int off;
    if (i < NW)          { s = Wq; off = i; }
    else if (i < 2 * NW) { s = Wk; off = i - NW; }
    else                 { s = Wv; off = i - 2 * NW; }
    float4 v = *(const float4*)(s + off);
    bf16x4 o;
    o[0] = (bf16_t)v.x; o[1] = (bf16_t)v.y; o[2] = (bf16_t)v.z; o[3] = (bf16_t)v.w;
    *(bf16x4*)(wqkv + i) = o;
  } else if (i < 4 * NW) {
    const int off = i - 3 * NW;
    float4 v = *(const float4*)(Wo + off);
    bf16x4 o;
    o[0] = (bf16_t)v.x; o[1] = (bf16_t)v.y; o[2] = (bf16_t)v.z; o[3] = (bf16_t)v.w;
    *(bf16x4*)(wob + off) = o;
  }
  if (t < 2304) qkvb[t] = t < 768 ? bq[t] : (t < 1536 ? bk[t - 768] : bv[t - 1536]);
}

// ---------------- fused QKV GEMM: qkv = xb @ Wqkv^T + bias ----------------
// Fragment-major LDS: 16B chunk c (f=c>>6, lane=c&63) holds row (f>>3)*64+((f>>1)&3)*16+(lane&15),
// cols (f&1)*32+(lane>>4)*8 .. +7. Every MFMA fragment read = base + lane*16B (conflict-free).
// V-region blocks compute C^T (swapped MFMA operands) so the [B,H,D,T] write coalesces.
// q pre-scaled by 1/sqrt(64)*log2(e).
__global__ __launch_bounds__(256) void gemm_qkv(
    const bf16_t* __restrict__ A, const bf16_t* __restrict__ B,
    const float* __restrict__ bias,
    bf16_t* __restrict__ qb, bf16_t* __restrict__ kb2, bf16_t* __restrict__ vtb) {
  __shared__ __align__(16) bf16_t As[8192];
  __shared__ __align__(16) bf16_t Bs[8192];
  const int K = 768;
  const int bm = blockIdx.x, bn = blockIdx.y;
  const int tid = threadIdx.x;
  const int w = tid >> 6, l = tid & 63, lg = l >> 4, ln = l & 15;
  const int wr = w >> 1, wc = w & 1;
  const int region = (bn * 128) / 768;
  // staging sources: thread stages chunks c_i = i*256 + tid (f = i*4 + w uniform/wave)
  const bf16_t* sA[4]; const bf16_t* sB[4];
#pragma unroll
  for (int i = 0; i < 4; ++i) {
    const int f = i * 4 + w;
    const int row = (f >> 3) * 64 + ((f >> 1) & 3) * 16 + (l & 15);
    const int col = (f & 1) * 32 + (l >> 4) * 8;
    sA[i] = A + (size_t)(bm * 128 + row) * K + col;
    sB[i] = B + (size_t)(bn * 128 + row) * K + col;
  }
  f32x4 acc[4][4] = {};
  for (int kb = 0; kb < K / 64; ++kb) {
#pragma unroll
    for (int i = 0; i < 4; ++i) {
      gld_lds16(sA[i], As + (i * 256 + w * 64) * 8);
      gld_lds16(sB[i], Bs + (i * 256 + w * 64) * 8);
      sA[i] += 64; sB[i] += 64;
    }
    __syncthreads();
#pragma unroll
    for (int kk = 0; kk < 2; ++kk) {
      bf16x8 af[4], bfr[4];
#pragma unroll
      for (int m = 0; m < 4; ++m) {
        af[m]  = *(const bf16x8*)(As + (wr * 8 + m * 2 + kk) * 512 + l * 8);
        bfr[m] = *(const bf16x8*)(Bs + (wc * 8 + m * 2 + kk) * 512 + l * 8);
      }
      if (region != 2) {
#pragma unroll
        for (int m = 0; m < 4; ++m)
#pragma unroll
          for (int n = 0; n < 4; ++n) acc[m][n] = MFMA16(af[m], bfr[n], acc[m][n]);
      } else {  // C^T for coalesced [B,H,D,T] writes
#pragma unroll
        for (int m = 0; m < 4; ++m)
#pragma unroll
          for (int n = 0; n < 4; ++n) acc[m][n] = MFMA16(bfr[n], af[m], acc[m][n]);
      }
    }
    __syncthreads();
  }
  if (region != 2) {
    const float scl = (region == 0) ? 0.18033688011112042f : 1.0f;  // 0.125*log2(e)
    bf16_t* dst = region == 0 ? qb : kb2;
#pragma unroll
    for (int m = 0; m < 4; ++m)
#pragma unroll
      for (int n = 0; n < 4; ++n)
#pragma unroll
        for (int j = 0; j < 4; ++j) {
          const int gm = bm * 128 + wr * 64 + m * 16 + lg * 4 + j;   // t
          const int gn = bn * 128 + wc * 64 + n * 16 + ln;           // qkv col
          const float v = (acc[m][n][j] + bias[gn]) * scl;
          const int c = gn - region * 768;
          const int bb = gm >> 12, tt = gm & 4095;
          const int hh = c >> 6, d = c & 63;
          dst[((size_t)(bb * 12 + hh) * 4096 + tt) * 64 + d] = (bf16_t)v;
        }
  } else {  // transposed acc: C-row = channel, C-col = t (lanes ln -> consecutive t)
#pragma unroll
    for (int m = 0; m < 4; ++m)
#pragma unroll
      for (int n = 0; n < 4; ++n)
#pragma unroll
        for (int j = 0; j < 4; ++j) {
          const int gn = bn * 128 + wc * 64 + n * 16 + lg * 4 + j;   // qkv col (channel)
          const int gm = bm * 128 + wr * 64 + m * 16 + ln;           // t
          const float v = acc[m][n][j] + bias[gn];
          const int c = gn - 1536;
          const int bb = gm >> 12, tt = gm & 4095;
          const int hh = c >> 6, d = c & 63;
          vtb[((size_t)(bb * 12 + hh) * 64 + d) * 4096 + tt] = (bf16_t)v;
        }
  }
}

// ---------------- flash attention (causal), in-block K-split (R7-verified) ----------------
__global__ __launch_bounds__(512) void attn_fwd(
    const bf16_t* __restrict__ q, const bf16_t* __restrict__ k,
    const bf16_t* __restrict__ vt, bf16_t* __restrict__ y) {
  __shared__ __align__(16) unsigned char SMEM[65536];
  bf16_t* Ks = (bf16_t*)SMEM;            // [dbuf][stream][4096]
  bf16_t* Vs = (bf16_t*)(SMEM + 32768);  // [dbuf][stream][4096]
  float*  osh = (float*)SMEM;            // combine: [4][32][64] f32
  float*  lsh = (float*)(SMEM + 32768);  // combine: [4][64] f32

  const int p = blockIdx.x;
  const int xcd = p & 7, slot = p >> 3;        // 96 slots per XCD
  const int hb = xcd + 8 * (slot % 3);         // 3 heads per XCD (L2-resident K/V)
  const int qt = 31 - slot / 3;                // heavy-first
  const int tid = threadIdx.x;
  const int w = tid >> 6, l = tid & 63, lq = l & 31, lh = l >> 5;
  const int wq = w >> 1, wc = w & 1;
  const size_t hbo = (size_t)hb * (4096 * 64);
  const bf16_t* qh = q + hbo;
  const bf16_t* kh = k + hbo;
  const bf16_t* vh = vt + hbo;

  const int q0 = qt * 128 + wq * 32;           // wave's first q row
  const int qidx = q0 + lq;                    // this lane's q row
  const int nst = qt + 1;                      // lockstep steps

  const int sr = ((tid >> 8) << 5) | (tid & 31);
  const int sc = ((((tid >> 6) & 3) << 1) | ((tid >> 5) & 1)) << 3;
  const bf16_t* k0src = kh + ((size_t)sr * 64 + sc);
  const bf16_t* k1src = k0src + 4096;
  const bf16_t* v0src = vh + ((size_t)sr * 4096 + sc);
  const bf16_t* v1src = v0src + 64;

  bf16x8 qf[4];
#pragma unroll
  for (int ds = 0; ds < 4; ++ds)
    qf[ds] = *(const bf16x8*)(qh + (size_t)qidx * 64 + 16 * ds + 8 * lh);

  gld_lds16(k0src, Ks + tid * 8);
  gld_lds16(k1src, Ks + 4096 + tid * 8);
  gld_lds16(v0src, Vs + tid * 8);
  gld_lds16(v1src, Vs + 4096 + tid * 8);
  __syncthreads();

  f32x16 o0 = {}, o1 = {};
  float lsum = 0.f;

  int cur = 0;
  for (int i = 0; i < nst; ++i) {
    if (i + 1 < nst) {
      bf16_t* kd = Ks + (cur ^ 1) * 8192;
      bf16_t* vd = Vs + (cur ^ 1) * 8192;
      gld_lds16(k0src + 8192, kd + tid * 8);
      gld_lds16(k1src + 8192, kd + 4096 + tid * 8);
      gld_lds16(v0src + 128, vd + tid * 8);
      gld_lds16(v1src + 128, vd + 4096 + tid * 8);
    }
    k0src += 8192; k1src += 8192; v0src += 128; v1src += 128;
    const int t = 2 * i + wc;
    if (t * 64 <= q0 + 31) {
      const int kvb = t * 64;
      const bool diag = (kvb + 63 > q0);
      const bf16_t* KsW = Ks + (cur * 2 + wc) * 4096;
      const bf16_t* VsW = Vs + (cur * 2 + wc) * 4096;
      u32 pq[2][8];
#pragma unroll
      for (int kb = 0; kb < 2; ++kb) {
        f32x16 st = {};
        __builtin_amdgcn_s_setprio(1);
#pragma unroll
        for (int ds = 0; ds < 4; ++ds) {
          bf16x8 kf = *(const bf16x8*)(KsW + (kb * 4 + ds) * 512 + l * 8);
          st = MFMA32(kf, qf[ds], st);
        }
        __builtin_amdgcn_s_setprio(0);
        float pv[16];
#pragma unroll
        for (int r = 0; r < 16; ++r) pv[r] = __builtin_amdgcn_exp2f(st[r]);
        if (diag) {
          const int kb0 = kvb + kb * 32 + 4 * lh;
#pragma unroll
          for (int r = 0; r < 16; ++r)
            if (kb0 + (r & 3) + 8 * (r >> 2) > qidx) pv[r] = 0.f;
        }
#pragma unroll
        for (int r = 0; r < 16; ++r) lsum += pv[r];
#pragma unroll
        for (int g = 0; g < 8; ++g) pq[kb][g] = cvt_pk_bf16(pv[2 * g], pv[2 * g + 1]);
#pragma unroll
        for (int ks2 = 0; ks2 < 2; ++ks2) {
          asm("v_permlane32_swap_b32 %0, %1" : "+v"(pq[kb][4 * ks2 + 0]), "+v"(pq[kb][4 * ks2 + 2]));
          asm("v_permlane32_swap_b32 %0, %1" : "+v"(pq[kb][4 * ks2 + 1]), "+v"(pq[kb][4 * ks2 + 3]));
        }
      }
      __builtin_amdgcn_s_setprio(1);
#pragma unroll
      for (int ks = 0; ks < 4; ++ks) {
        bf16x8 pa = *(const bf16x8*)&pq[ks >> 1][(ks & 1) * 4];
        bf16x8 v0 = *(const bf16x8*)(VsW + ks * 512 + l * 8);
        bf16x8 v1 = *(const bf16x8*)(VsW + (4 + ks) * 512 + l * 8);
        o0 = MFMA32(pa, v0, o0);
        o1 = MFMA32(pa, v1, o1);
      }
      __builtin_amdgcn_s_setprio(0);
    }
    __syncthreads();
    cur ^= 1;
  }
  lsum += __shfl_xor(lsum, 32);

  if (wc == 1) {
#pragma unroll
    for (int r = 0; r < 16; ++r) {
      osh[wq * 2048 + r * 64 + l] = o0[r];
      osh[wq * 2048 + (16 + r) * 64 + l] = o1[r];
    }
    lsh[wq * 64 + l] = lsum;
  }
  __syncthreads();
  if (wc == 0) {
    lsum += lsh[wq * 64 + l];
#pragma unroll
    for (int r = 0; r < 16; ++r) {
      o0[r] += osh[wq * 2048 + r * 64 + l];
      o1[r] += osh[wq * 2048 + (16 + r) * 64 + l];
    }
    float linv[16];
#pragma unroll
    for (int r = 0; r < 16; ++r)
      linv[r] = 1.0f / __shfl(lsum, (r & 3) + 8 * (r >> 2) + 4 * lh);
    const int b = hb / 12, h = hb - b * 12;
#pragma unroll
    for (int r = 0; r < 16; ++r) {
      const int row = q0 + (r & 3) + 8 * (r >> 2) + 4 * lh;
      bf16_t* yr = y + ((size_t)b * 4096 + row) * 768 + h * 64 + lq;
      yr[0]  = (bf16_t)(o0[r] * linv[r]);
      yr[32] = (bf16_t)(o1[r] * linv[r]);
    }
  }
}

// ---------------- output GEMM: out = y @ Wo^T + bo (fp32 out), fragment-major LDS ----------------
__global__ __launch_bounds__(256) void gemm_out(
    const bf16_t* __restrict__ A, const bf16_t* __restrict__ B,
    const float* __restrict__ bias, float* __restrict__ out) {
  __shared__ __align__(16) bf16_t As[8192];
  __shared__ __align__(16) bf16_t Bs[8192];
  const int K = 768;
  const int bm = blockIdx.x, bn = blockIdx.y;
  const int tid = threadIdx.x;
  const int w = tid >> 6, l = tid & 63, lg = l >> 4, ln = l & 15;
  const int wr = w >> 1, wc = w & 1;
  const bf16_t* sA[4]; const bf16_t* sB[4];
#pragma unroll
  for (int i = 0; i < 4; ++i) {
    const int f = i * 4 + w;
    const int row = (f >> 3) * 64 + ((f >> 1) & 3) * 16 + (l & 15);
    const int col = (f & 1) * 32 + (l >> 4) * 8;
    sA[i] = A + (size_t)(bm * 128 + row) * K + col;
    sB[i] = B + (size_t)(bn * 128 + row) * K + col;
  }
  f32x4 acc[4][4] = {};
  for (int kb = 0; kb < K / 64; ++kb) {
#pragma unroll
    for (int i = 0; i < 4; ++i) {
      gld_lds16(sA[i], As + (i * 256 + w * 64) * 8);
      gld_lds16(sB[i], Bs + (i * 256 + w * 64) * 8);
      sA[i] += 64; sB[i] += 64;
    }
    __syncthreads();
#pragma unroll
    for (int kk = 0; kk < 2; ++kk) {
      bf16x8 af[4], bfr[4];
#pragma unroll
      for (int m = 0; m < 4; ++m) {
        af[m]  = *(const bf16x8*)(As + (wr * 8 + m * 2 + kk) * 512 + l * 8);
        bfr[m] = *(const bf16x8*)(Bs + (wc * 8 + m * 2 + kk) * 512 + l * 8);
      }
#pragma unroll
      for (int m = 0; m < 4; ++m)
#pragma unroll
        for (int n = 0; n < 4; ++n) acc[m][n] = MFMA16(af[m], bfr[n], acc[m][n]);
    }
    __syncthreads();
  }
  const int gn0 = bn * 128 + wc * 64;
#pragma unroll
  for (int m = 0; m < 4; ++m) {
#pragma unroll
    for (int n = 0; n < 4; ++n) {
#pragma unroll
      for (int j = 0; j < 4; ++j) {
        const int gm = bm * 128 + wr * 64 + m * 16 + lg * 4 + j;
        const int gn = gn0 + n * 16 + ln;
        out[(size_t)gm * 768 + gn] = acc[m][n][j] + bias[gn];
      }
    }
  }
}

// ---------------- launch ----------------
extern "C" void kernel_launch(void* const* d_in, const int* in_sizes, int n_in,
                              void* d_out, int out_size, void* d_ws, size_t ws_size,
                              hipStream_t stream) {
  const float* x  = (const float*)d_in[0];
  const float* Wq = (const float*)d_in[1];
  const float* bq = (const float*)d_in[2];
  const float* Wk = (const float*)d_in[3];
  const float* bk = (const float*)d_in[4];
  const float* Wv = (const float*)d_in[5];
  const float* bv = (const float*)d_in[6];
  const float* Wo = (const float*)d_in[7];
  const float* bo = (const float*)d_in[8];
  float* out = (float*)d_out;

  const int M = 8192, C = 768, QKV = 2304;
  bf16_t* xb   = (bf16_t*)d_ws;                    // [8192][768]
  bf16_t* wqkv = xb + (size_t)M * C;               // [2304][768]
  bf16_t* wob  = wqkv + (size_t)QKV * C;           // [768][768]
  float*  qkvb = (float*)(wob + (size_t)C * C);    // [2304]
  bf16_t* qbuf = (bf16_t*)(qkvb + QKV);            // [B,H,T,D] (q pre-scaled)
  bf16_t* kbuf = qbuf + (size_t)M * C;             // [B,H,T,D]
  bf16_t* vtb  = kbuf + (size_t)M * C;             // [B,H,D,T]
  bf16_t* yb   = xb;                               // reuse xb (dead after gemm_qkv)

  cast_f32_bf16<<<6144, 256, 0, stream>>>(x, xb, M * C);
  prep_w<<<2304, 256, 0, stream>>>(Wq, Wk, Wv, Wo, bq, bk, bv, wqkv, wob, qkvb);

  gemm_qkv<<<dim3(64, 18), 256, 0, stream>>>(xb, wqkv, qkvb, qbuf, kbuf, vtb);
  attn_fwd<<<768, 512, 0, stream>>>(qbuf, kbuf, vtb, yb);
  gemm_out<<<dim3(64, 6), 256, 0, stream>>>(yb, wob, bo, out);
}

// Round 9
// 173.209 us; speedup vs baseline: 1.2360x; 1.2360x over previous
//
#include <hip/hip_runtime.h>

typedef __bf16 bf16_t;
typedef __bf16 bf16x4 __attribute__((ext_vector_type(4)));
typedef __bf16 bf16x8 __attribute__((ext_vector_type(8)));
typedef float  f32x4  __attribute__((ext_vector_type(4)));
typedef float  f32x16 __attribute__((ext_vector_type(16)));
typedef unsigned int u32;

#define MFMA16(a, b, c) __builtin_amdgcn_mfma_f32_16x16x32_bf16((a), (b), (c), 0, 0, 0)
#define MFMA32(a, b, c) __builtin_amdgcn_mfma_f32_32x32x16_bf16((a), (b), (c), 0, 0, 0)

__device__ __forceinline__ void gld_lds16(const bf16_t* g, bf16_t* l) {
  __builtin_amdgcn_global_load_lds((__attribute__((address_space(1))) void*)g,
                                   (__attribute__((address_space(3))) void*)l, 16, 0, 0);
}
__device__ __forceinline__ u32 cvt_pk_bf16(float lo, float hi) {
  u32 r;
  asm("v_cvt_pk_bf16_f32 %0, %1, %2" : "=v"(r) : "v"(lo), "v"(hi));
  return r;
}

// ---------------- prep: x cast (big) ----------------
__global__ void cast_f32_bf16(const float* __restrict__ s, bf16_t* __restrict__ d, int n) {
  int i = (blockIdx.x * blockDim.x + threadIdx.x) * 4;
  if (i >= n) return;
  float4 v = *(const float4*)(s + i);
  bf16x4 o;
  o[0] = (bf16_t)v.x; o[1] = (bf16_t)v.y; o[2] = (bf16_t)v.z; o[3] = (bf16_t)v.w;
  *(bf16x4*)(d + i) = o;
}

// ---------------- prep: all weight casts + bias concat in one launch ----------------
__global__ void prep_w(const float* __restrict__ Wq, const float* __restrict__ Wk,
                       const float* __restrict__ Wv, const float* __restrict__ Wo,
                       const float* __restrict__ bq, const float* __restrict__ bk,
                       const float* __restrict__ bv,
                       bf16_t* __restrict__ wqkv, bf16_t* __restrict__ wob,
                       float* __restrict__ qkvb) {
  const int NW = 768 * 768;
  const int t = blockIdx.x * 256 + threadIdx.x;
  const int i = t * 4;
  if (i < 3 * NW) {
    const float* s; int off;
    if (i < NW)          { s = Wq; off = i; }
    else if (i < 2 * NW) { s = Wk; off = i - NW; }
    else                 { s = Wv; off = i - 2 * NW; }
    float4 v = *(const float4*)(s + off);
    bf16x4 o;
    o[0] = (bf16_t)v.x; o[1] = (bf16_t)v.y; o[2] = (bf16_t)v.z; o[3] = (bf16_t)v.w;
    *(bf16x4*)(wqkv + i) = o;
  } else if (i < 4 * NW) {
    const int off = i - 3 * NW;
    float4 v = *(const float4*)(Wo + off);
    bf16x4 o;
    o[0] = (bf16_t)v.x; o[1] = (bf16_t)v.y; o[2] = (bf16_t)v.z; o[3] = (bf16_t)v.w;
    *(bf16x4*)(wob + off) = o;
  }
  if (t < 2304) qkvb[t] = t < 768 ? bq[t] : (t < 1536 ? bk[t - 768] : bv[t - 1536]);
}

// ---------------- fused QKV GEMM: qkv = xb @ Wqkv^T + bias ----------------
// R7 contiguous staging + chunk-XOR swizzle: LDS[row][j] holds global col-chunk
// j^(row&7) (16B chunks, 8 per 128B row). Staging stays within each 128B row
// (coalesced); fragment reads XOR the same way -> bank-floor, ~0 conflicts.
// V-region blocks compute C^T (swapped MFMA operands) so [B,H,D,T] writes coalesce.
// q pre-scaled by 1/sqrt(64)*log2(e).
__global__ __launch_bounds__(256) void gemm_qkv(
    const bf16_t* __restrict__ A, const bf16_t* __restrict__ B,
    const float* __restrict__ bias,
    bf16_t* __restrict__ qb, bf16_t* __restrict__ kb2, bf16_t* __restrict__ vtb) {
  __shared__ __align__(16) bf16_t As[128 * 64];
  __shared__ __align__(16) bf16_t Bs[128 * 64];
  const int K = 768;
  const int bm = blockIdx.x, bn = blockIdx.y;
  const int tid = threadIdx.x;
  const int w = tid >> 6, l = tid & 63, lg = l >> 4, ln = l & 15;
  const int wr = w >> 1, wc = w & 1;
  const int lr8 = l >> 3, lc8 = l & 7;
  const int region = (bn * 128) / 768;
  const int ln7 = ln & 7;
  f32x4 acc[4][4] = {};
  for (int kb = 0; kb < K / 64; ++kb) {
    const int k0 = kb * 64;
#pragma unroll
    for (int i = 0; i < 4; ++i) {
      const int row = w * 32 + i * 8 + lr8;
      const int so = k0 + ((lc8 ^ (row & 7)) << 3);     // pre-swizzled source col
      gld_lds16(A + (size_t)(bm * 128 + row) * K + so, As + (w * 32 + i * 8) * 64 + l * 8);
      gld_lds16(B + (size_t)(bn * 128 + row) * K + so, Bs + (w * 32 + i * 8) * 64 + l * 8);
    }
    __syncthreads();
#pragma unroll
    for (int kk = 0; kk < 2; ++kk) {
      bf16x8 af[4], bfr[4];
#pragma unroll
      for (int m = 0; m < 4; ++m) {
        const int jc = ((kk * 4 + lg) ^ ln7) << 3;      // swizzled chunk read
        af[m]  = *(const bf16x8*)(As + (wr * 64 + m * 16 + ln) * 64 + jc);
        bfr[m] = *(const bf16x8*)(Bs + (wc * 64 + m * 16 + ln) * 64 + jc);
      }
      if (region != 2) {
#pragma unroll
        for (int m = 0; m < 4; ++m)
#pragma unroll
          for (int n = 0; n < 4; ++n) acc[m][n] = MFMA16(af[m], bfr[n], acc[m][n]);
      } else {  // C^T for coalesced [B,H,D,T] writes
#pragma unroll
        for (int m = 0; m < 4; ++m)
#pragma unroll
          for (int n = 0; n < 4; ++n) acc[m][n] = MFMA16(bfr[n], af[m], acc[m][n]);
      }
    }
    __syncthreads();
  }
  if (region != 2) {
    const float scl = (region == 0) ? 0.18033688011112042f : 1.0f;  // 0.125*log2(e)
    bf16_t* dst = region == 0 ? qb : kb2;
#pragma unroll
    for (int m = 0; m < 4; ++m)
#pragma unroll
      for (int n = 0; n < 4; ++n)
#pragma unroll
        for (int j = 0; j < 4; ++j) {
          const int gm = bm * 128 + wr * 64 + m * 16 + lg * 4 + j;   // t
          const int gn = bn * 128 + wc * 64 + n * 16 + ln;           // qkv col
          const float v = (acc[m][n][j] + bias[gn]) * scl;
          const int c = gn - region * 768;
          const int bb = gm >> 12, tt = gm & 4095;
          const int hh = c >> 6, d = c & 63;
          dst[((size_t)(bb * 12 + hh) * 4096 + tt) * 64 + d] = (bf16_t)v;
        }
  } else {  // transposed acc: C-row = channel, C-col = t (lanes ln -> consecutive t)
#pragma unroll
    for (int m = 0; m < 4; ++m)
#pragma unroll
      for (int n = 0; n < 4; ++n)
#pragma unroll
        for (int j = 0; j < 4; ++j) {
          const int gn = bn * 128 + wc * 64 + n * 16 + lg * 4 + j;   // qkv col (channel)
          const int gm = bm * 128 + wr * 64 + m * 16 + ln;           // t
          const float v = acc[m][n][j] + bias[gn];
          const int c = gn - 1536;
          const int bb = gm >> 12, tt = gm & 4095;
          const int hh = c >> 6, d = c & 63;
          vtb[((size_t)(bb * 12 + hh) * 64 + d) * 4096 + tt] = (bf16_t)v;
        }
  }
}

// ---------------- flash attention (causal), in-block K-split (R7-verified) ----------------
__global__ __launch_bounds__(512) void attn_fwd(
    const bf16_t* __restrict__ q, const bf16_t* __restrict__ k,
    const bf16_t* __restrict__ vt, bf16_t* __restrict__ y) {
  __shared__ __align__(16) unsigned char SMEM[65536];
  bf16_t* Ks = (bf16_t*)SMEM;            // [dbuf][stream][4096]
  bf16_t* Vs = (bf16_t*)(SMEM + 32768);  // [dbuf][stream][4096]
  float*  osh = (float*)SMEM;            // combine: [4][32][64] f32
  float*  lsh = (float*)(SMEM + 32768);  // combine: [4][64] f32

  const int p = blockIdx.x;
  const int xcd = p & 7, slot = p >> 3;        // 96 slots per XCD
  const int hb = xcd + 8 * (slot % 3);         // 3 heads per XCD (L2-resident K/V)
  const int qt = 31 - slot / 3;                // heavy-first
  const int tid = threadIdx.x;
  const int w = tid >> 6, l = tid & 63, lq = l & 31, lh = l >> 5;
  const int wq = w >> 1, wc = w & 1;
  const size_t hbo = (size_t)hb * (4096 * 64);
  const bf16_t* qh = q + hbo;
  const bf16_t* kh = k + hbo;
  const bf16_t* vh = vt + hbo;

  const int q0 = qt * 128 + wq * 32;           // wave's first q row
  const int qidx = q0 + lq;                    // this lane's q row
  const int nst = qt + 1;                      // lockstep steps

  const int sr = ((tid >> 8) << 5) | (tid & 31);
  const int sc = ((((tid >> 6) & 3) << 1) | ((tid >> 5) & 1)) << 3;
  const bf16_t* k0src = kh + ((size_t)sr * 64 + sc);
  const bf16_t* k1src = k0src + 4096;
  const bf16_t* v0src = vh + ((size_t)sr * 4096 + sc);
  const bf16_t* v1src = v0src + 64;

  bf16x8 qf[4];
#pragma unroll
  for (int ds = 0; ds < 4; ++ds)
    qf[ds] = *(const bf16x8*)(qh + (size_t)qidx * 64 + 16 * ds + 8 * lh);

  gld_lds16(k0src, Ks + tid * 8);
  gld_lds16(k1src, Ks + 4096 + tid * 8);
  gld_lds16(v0src, Vs + tid * 8);
  gld_lds16(v1src, Vs + 4096 + tid * 8);
  __syncthreads();

  f32x16 o0 = {}, o1 = {};
  float lsum = 0.f;

  int cur = 0;
  for (int i = 0; i < nst; ++i) {
    if (i + 1 < nst) {
      bf16_t* kd = Ks + (cur ^ 1) * 8192;
      bf16_t* vd = Vs + (cur ^ 1) * 8192;
      gld_lds16(k0src + 8192, kd + tid * 8);
      gld_lds16(k1src + 8192, kd + 4096 + tid * 8);
      gld_lds16(v0src + 128, vd + tid * 8);
      gld_lds16(v1src + 128, vd + 4096 + tid * 8);
    }
    k0src += 8192; k1src += 8192; v0src += 128; v1src += 128;
    const int t = 2 * i + wc;
    if (t * 64 <= q0 + 31) {
      const int kvb = t * 64;
      const bool diag = (kvb + 63 > q0);
      const bf16_t* KsW = Ks + (cur * 2 + wc) * 4096;
      const bf16_t* VsW = Vs + (cur * 2 + wc) * 4096;
      u32 pq[2][8];
#pragma unroll
      for (int kb = 0; kb < 2; ++kb) {
        f32x16 st = {};
        __builtin_amdgcn_s_setprio(1);
#pragma unroll
        for (int ds = 0; ds < 4; ++ds) {
          bf16x8 kf = *(const bf16x8*)(KsW + (kb * 4 + ds) * 512 + l * 8);
          st = MFMA32(kf, qf[ds], st);
        }
        __builtin_amdgcn_s_setprio(0);
        float pv[16];
#pragma unroll
        for (int r = 0; r < 16; ++r) pv[r] = __builtin_amdgcn_exp2f(st[r]);
        if (diag) {
          const int kb0 = kvb + kb * 32 + 4 * lh;
#pragma unroll
          for (int r = 0; r < 16; ++r)
            if (kb0 + (r & 3) + 8 * (r >> 2) > qidx) pv[r] = 0.f;
        }
#pragma unroll
        for (int r = 0; r < 16; ++r) lsum += pv[r];
#pragma unroll
        for (int g = 0; g < 8; ++g) pq[kb][g] = cvt_pk_bf16(pv[2 * g], pv[2 * g + 1]);
#pragma unroll
        for (int ks2 = 0; ks2 < 2; ++ks2) {
          asm("v_permlane32_swap_b32 %0, %1" : "+v"(pq[kb][4 * ks2 + 0]), "+v"(pq[kb][4 * ks2 + 2]));
          asm("v_permlane32_swap_b32 %0, %1" : "+v"(pq[kb][4 * ks2 + 1]), "+v"(pq[kb][4 * ks2 + 3]));
        }
      }
      __builtin_amdgcn_s_setprio(1);
#pragma unroll
      for (int ks = 0; ks < 4; ++ks) {
        bf16x8 pa = *(const bf16x8*)&pq[ks >> 1][(ks & 1) * 4];
        bf16x8 v0 = *(const bf16x8*)(VsW + ks * 512 + l * 8);
        bf16x8 v1 = *(const bf16x8*)(VsW + (4 + ks) * 512 + l * 8);
        o0 = MFMA32(pa, v0, o0);
        o1 = MFMA32(pa, v1, o1);
      }
      __builtin_amdgcn_s_setprio(0);
    }
    __syncthreads();
    cur ^= 1;
  }
  lsum += __shfl_xor(lsum, 32);

  if (wc == 1) {
#pragma unroll
    for (int r = 0; r < 16; ++r) {
      osh[wq * 2048 + r * 64 + l] = o0[r];
      osh[wq * 2048 + (16 + r) * 64 + l] = o1[r];
    }
    lsh[wq * 64 + l] = lsum;
  }
  __syncthreads();
  if (wc == 0) {
    lsum += lsh[wq * 64 + l];
#pragma unroll
    for (int r = 0; r < 16; ++r) {
      o0[r] += osh[wq * 2048 + r * 64 + l];
      o1[r] += osh[wq * 2048 + (16 + r) * 64 + l];
    }
    float linv[16];
#pragma unroll
    for (int r = 0; r < 16; ++r)
      linv[r] = 1.0f / __shfl(lsum, (r & 3) + 8 * (r >> 2) + 4 * lh);
    const int b = hb / 12, h = hb - b * 12;
#pragma unroll
    for (int r = 0; r < 16; ++r) {
      const int row = q0 + (r & 3) + 8 * (r >> 2) + 4 * lh;
      bf16_t* yr = y + ((size_t)b * 4096 + row) * 768 + h * 64 + lq;
      yr[0]  = (bf16_t)(o0[r] * linv[r]);
      yr[32] = (bf16_t)(o1[r] * linv[r]);
    }
  }
}

// ---------------- output GEMM: out = y @ Wo^T + bo (fp32), swizzled LDS ----------------
__global__ __launch_bounds__(256) void gemm_out(
    const bf16_t* __restrict__ A, const bf16_t* __restrict__ B,
    const float* __restrict__ bias, float* __restrict__ out) {
  __shared__ __align__(16) bf16_t As[128 * 64];
  __shared__ __align__(16) bf16_t Bs[128 * 64];
  const int K = 768;
  const int bm = blockIdx.x, bn = blockIdx.y;
  const int tid = threadIdx.x;
  const int w = tid >> 6, l = tid & 63, lg = l >> 4, ln = l & 15;
  const int wr = w >> 1, wc = w & 1;
  const int lr8 = l >> 3, lc8 = l & 7;
  const int ln7 = ln & 7;
  f32x4 acc[4][4] = {};
  for (int kb = 0; kb < K / 64; ++kb) {
    const int k0 = kb * 64;
#pragma unroll
    for (int i = 0; i < 4; ++i) {
      const int row = w * 32 + i * 8 + lr8;
      const int so = k0 + ((lc8 ^ (row & 7)) << 3);
      gld_lds16(A + (size_t)(bm * 128 + row) * K + so, As + (w * 32 + i * 8) * 64 + l * 8);
      gld_lds16(B + (size_t)(bn * 128 + row) * K + so, Bs + (w * 32 + i * 8) * 64 + l * 8);
    }
    __syncthreads();
#pragma unroll
    for (int kk = 0; kk < 2; ++kk) {
      bf16x8 af[4], bfr[4];
#pragma unroll
      for (int m = 0; m < 4; ++m) {
        const int jc = ((kk * 4 + lg) ^ ln7) << 3;
        af[m]  = *(const bf16x8*)(As + (wr * 64 + m * 16 + ln) * 64 + jc);
        bfr[m] = *(const bf16x8*)(Bs + (wc * 64 + m * 16 + ln) * 64 + jc);
      }
#pragma unroll
      for (int m = 0; m < 4; ++m)
#pragma unroll
        for (int n = 0; n < 4; ++n) acc[m][n] = MFMA16(af[m], bfr[n], acc[m][n]);
    }
    __syncthreads();
  }
  const int gn0 = bn * 128 + wc * 64;
#pragma unroll
  for (int m = 0; m < 4; ++m) {
#pragma unroll
    for (int n = 0; n < 4; ++n) {
#pragma unroll
      for (int j = 0; j < 4; ++j) {
        const int gm = bm * 128 + wr * 64 + m * 16 + lg * 4 + j;
        const int gn = gn0 + n * 16 + ln;
        out[(size_t)gm * 768 + gn] = acc[m][n][j] + bias[gn];
      }
    }
  }
}

// ---------------- launch ----------------
extern "C" void kernel_launch(void* const* d_in, const int* in_sizes, int n_in,
                              void* d_out, int out_size, void* d_ws, size_t ws_size,
                              hipStream_t stream) {
  const float* x  = (const float*)d_in[0];
  const float* Wq = (const float*)d_in[1];
  const float* bq = (const float*)d_in[2];
  const float* Wk = (const float*)d_in[3];
  const float* bk = (const float*)d_in[4];
  const float* Wv = (const float*)d_in[5];
  const float* bv = (const float*)d_in[6];
  const float* Wo = (const float*)d_in[7];
  const float* bo = (const float*)d_in[8];
  float* out = (float*)d_out;

  const int M = 8192, C = 768, QKV = 2304;
  bf16_t* xb   = (bf16_t*)d_ws;                    // [8192][768]
  bf16_t* wqkv = xb + (size_t)M * C;               // [2304][768]
  bf16_t* wob  = wqkv + (size_t)QKV * C;           // [768][768]
  float*  qkvb = (float*)(wob + (size_t)C * C);    // [2304]
  bf16_t* qbuf = (bf16_t*)(qkvb + QKV);            // [B,H,T,D] (q pre-scaled)
  bf16_t* kbuf = qbuf + (size_t)M * C;             // [B,H,T,D]
  bf16_t* vtb  = kbuf + (size_t)M * C;             // [B,H,D,T]
  bf16_t* yb   = xb;                               // reuse xb (dead after gemm_qkv)

  cast_f32_bf16<<<6144, 256, 0, stream>>>(x, xb, M * C);
  prep_w<<<2304, 256, 0, stream>>>(Wq, Wk, Wv, Wo, bq, bk, bv, wqkv, wob, qkvb);

  gemm_qkv<<<dim3(64, 18), 256, 0, stream>>>(xb, wqkv, qkvb, qbuf, kbuf, vtb);
  attn_fwd<<<768, 512, 0, stream>>>(qbuf, kbuf, vtb, yb);
  gemm_out<<<dim3(64, 6), 256, 0, stream>>>(yb, wob, bo, out);
}